// Round 6
// baseline (12079.153 us; speedup 1.0000x reference)
//
#include <hip/hip_runtime.h>

// LSTM T=4096, IN=32, H=512, OUT=32, 3 layers + projection.
// R6: kill the spill by halving per-lane weights.
//   R3/R5 post-mortem: 128 w-floats/lane NEVER stays in registers (VGPR=88/116,
//   scratch spill; R5 WRITE_SIZE 98MB = 50 hp + 48 spill-writeback). Fix:
//   64 WGs/layer x 512 thr; wave owns ONE column (4 gate rows x 16 lanes) ->
//   w[]=64 floats/lane. 64+~50 working << 256 VGPR cap -> no spill.
// Layout: 192 WGs; layer=blk/64, g=blk%64; col=g*8+wv; lane=rl*16+j,
//   rl=gate(0..3), j=k-chunk(0..15).
//   Layers 1/2: K=1024 concat [prev-h(512); own-h(512)]; lane j covers
//   [j*64,(j+1)*64): j<8 -> Wih, j>=8 -> Whh. Layer 0: 32 h-k + 2 x-k.
//   Bank-stagger (i+j)&15 applied at WEIGHT LOAD (global side, R4's lesson):
//   dot indexes w[] with loop constants only; LDS conflict-free (2-way max).
//   In-wave butterfly (xor 1,2,4,8) -> row sums; lane0 gates+publish.
// Handoff: packed u64 {seq-tag:32 | value:32} relaxed agent-scope atomics
//   (per-instr coherent, no cache-wide fences, safe under XCD L2 split).

#define T_SEQ 4096
#define HDIM  512
#define NWG_L 64
#define NTH   512

typedef unsigned long long u64;

__device__ __forceinline__ u64 cohLoad(const u64* p) {
    return __hip_atomic_load(p, __ATOMIC_RELAXED, __HIP_MEMORY_SCOPE_AGENT);
}
__device__ __forceinline__ void cohStore(u64* p, u64 v) {
    __hip_atomic_store(p, v, __ATOMIC_RELAXED, __HIP_MEMORY_SCOPE_AGENT);
}
__device__ __forceinline__ float fsigmoid(float x) {
    return __builtin_amdgcn_rcpf(1.f + __expf(-x));
}
__device__ __forceinline__ float ftanh(float x) {
    float e = __expf(2.f * fabsf(x));           // +inf ok -> t = 1
    float t = 1.f - 2.f * __builtin_amdgcn_rcpf(e + 1.f);
    return copysignf(t, x);
}

// ---------------------------------------------------------------------------
// Tiled fp32 GEMM (final projection): C[M][N] = A[M][K] * B[N][K]^T + bias[n]
// ---------------------------------------------------------------------------
template <int BM, int BN, int BK>
__global__ __launch_bounds__(256)
void gemm_abt(const float* __restrict__ A, const float* __restrict__ B,
              const float* __restrict__ bias1,
              float* __restrict__ C, int M, int N, int K) {
    constexpr int NTX = BN / 4;
    constexpr int NTY = 256 / NTX;
    constexpr int TM  = BM / NTY;
    __shared__ float As[BM][BK + 1];
    __shared__ float Bs[BN][BK + 1];

    const int tid = threadIdx.x;
    const int tx = tid % NTX;
    const int ty = tid / NTX;
    const int m0 = blockIdx.y * BM;
    const int n0 = blockIdx.x * BN;

    float acc[TM][4];
    #pragma unroll
    for (int i = 0; i < TM; ++i)
        #pragma unroll
        for (int j = 0; j < 4; ++j) acc[i][j] = 0.f;

    for (int k0 = 0; k0 < K; k0 += BK) {
        constexpr int AV = BM * BK / 4;
        #pragma unroll
        for (int i = tid; i < AV; i += 256) {
            int r = i / (BK / 4), c4 = i % (BK / 4);
            float4 v = *(const float4*)(A + (size_t)(m0 + r) * K + k0 + c4 * 4);
            As[r][c4 * 4 + 0] = v.x; As[r][c4 * 4 + 1] = v.y;
            As[r][c4 * 4 + 2] = v.z; As[r][c4 * 4 + 3] = v.w;
        }
        constexpr int BV = BN * BK / 4;
        #pragma unroll
        for (int i = tid; i < BV; i += 256) {
            int r = i / (BK / 4), c4 = i % (BK / 4);
            float4 v = *(const float4*)(B + (size_t)(n0 + r) * K + k0 + c4 * 4);
            Bs[r][c4 * 4 + 0] = v.x; Bs[r][c4 * 4 + 1] = v.y;
            Bs[r][c4 * 4 + 2] = v.z; Bs[r][c4 * 4 + 3] = v.w;
        }
        __syncthreads();
        #pragma unroll
        for (int kk = 0; kk < BK; ++kk) {
            float a[TM], b[4];
            #pragma unroll
            for (int i = 0; i < TM; ++i) a[i] = As[ty * TM + i][kk];
            #pragma unroll
            for (int j = 0; j < 4; ++j) b[j] = Bs[tx * 4 + j][kk];
            #pragma unroll
            for (int i = 0; i < TM; ++i)
                #pragma unroll
                for (int j = 0; j < 4; ++j) acc[i][j] += a[i] * b[j];
        }
        __syncthreads();
    }

    #pragma unroll
    for (int j = 0; j < 4; ++j) {
        float bv = bias1 ? bias1[n0 + tx * 4 + j] : 0.f;
        #pragma unroll
        for (int i = 0; i < TM; ++i) acc[i][j] += bv;
    }
    #pragma unroll
    for (int i = 0; i < TM; ++i) {
        int m = m0 + ty * TM + i;
        float4 v = make_float4(acc[i][0], acc[i][1], acc[i][2], acc[i][3]);
        *(float4*)(C + (size_t)m * N + n0 + tx * 4) = v;
    }
}

// ---------------------------------------------------------------------------
__global__ void unpack_h(const u64* __restrict__ hp, float* __restrict__ out,
                         int n) {
    int i = blockIdx.x * blockDim.x + threadIdx.x;
    if (i < n) out[i] = __uint_as_float((unsigned)hp[i]);
}

// ---------------------------------------------------------------------------
__global__ __launch_bounds__(NTH, 2)
void lstm_fused(const float* __restrict__ seq,
                const float* __restrict__ Wih1, const float* __restrict__ Whh1,
                const float* __restrict__ bih1, const float* __restrict__ bhh1,
                const float* __restrict__ Wih2, const float* __restrict__ Whh2,
                const float* __restrict__ bih2, const float* __restrict__ bhh2,
                const float* __restrict__ Wih3, const float* __restrict__ Whh3,
                const float* __restrict__ bih3, const float* __restrict__ bhh3,
                u64* __restrict__ hp) {
    __shared__ __align__(16) float h_in[2][1024];   // [prev-h | own-h]
    __shared__ __align__(16) float x_lds[2][32];

    const int blk   = blockIdx.x;
    const int layer = blk >> 6;          // /64
    const int g     = blk & 63;
    const int tid   = threadIdx.x;
    const int wv    = tid >> 6;          // 0..7
    const int lane  = tid & 63;
    const int rl    = lane >> 4;         // gate 0..3 (i,f,g,o)
    const int j     = lane & 15;         // k-chunk 0..15
    const int col   = g * 8 + wv;        // this wave's h column
    const int grow  = rl * HDIM + col;   // global gate row

    const float* Wih = layer == 0 ? Wih1 : (layer == 1 ? Wih2 : Wih3);
    const float* Whh = layer == 0 ? Whh1 : (layer == 1 ? Whh2 : Whh3);
    const float* bih = layer == 0 ? bih1 : (layer == 1 ? bih2 : bih3);
    const float* bhh = layer == 0 ? bhh1 : (layer == 1 ? bhh2 : bhh3);

    // ---- 64 weights/lane into registers, permuted by the bank-stagger so
    //      the dot loop reads w[i] with loop-constant indices only.
    float w[64];
    #pragma unroll
    for (int m = 0; m < 64; ++m) w[m] = 0.f;
    if (layer == 0) {
        // h chunk: 32 k -> w[0..31] permuted (i+j)&7; x chunk: w[32..33]
        const float* wp = Whh + (size_t)grow * HDIM + j * 32;
        #pragma unroll
        for (int i = 0; i < 8; ++i) {
            int src = (i + j) & 7;                 // global-side index: safe
            float4 v = ((const float4*)wp)[src];
            w[4*i+0]=v.x; w[4*i+1]=v.y; w[4*i+2]=v.z; w[4*i+3]=v.w;
        }
        float2 xw = *(const float2*)(Wih + (size_t)grow * 32 + 2 * j);
        w[32] = xw.x; w[33] = xw.y;
    } else {
        const float* wp = (j < 8)
            ? Wih + (size_t)grow * HDIM + j * 64
            : Whh + (size_t)grow * HDIM + (j - 8) * 64;
        #pragma unroll
        for (int i = 0; i < 16; ++i) {
            int src = (i + j) & 15;
            float4 v = ((const float4*)wp)[src];
            w[4*i+0]=v.x; w[4*i+1]=v.y; w[4*i+2]=v.z; w[4*i+3]=v.w;
        }
    }
    #pragma unroll
    for (int m = 0; m < 64; ++m) asm volatile("" : "+v"(w[m]));

    const float brow = bih[grow] + bhh[grow];   // bias of this lane's row

    u64*       hpOwn  = hp + (size_t)layer * T_SEQ * HDIM;
    const u64* hpPrev = hp + (size_t)(layer > 0 ? layer - 1 : 0) * T_SEQ * HDIM;

    float c = 0.f;   // cell state (lane 0 of each wave)

    for (unsigned t = 0; t < T_SEQ; ++t) {
        const int pb = t & 1;
        // ---- stage inputs (poll fused with data read) ----
        if (layer == 0) {
            float hv = 0.f;
            if (t > 0) {
                const u64* ph = hpOwn + (size_t)(t - 1) * HDIM + tid;
                u64 v;
                do { v = cohLoad(ph); } while ((unsigned)(v >> 32) != t);
                hv = __uint_as_float((unsigned)v);
            }
            h_in[pb][tid] = hv;
            if (wv == 7 && lane < 32)
                x_lds[pb][lane] = seq[(size_t)t * 32 + lane];
        } else {
            const u64* px = hpPrev + (size_t)t * HDIM + tid;   // prev-layer h[t]
            u64 va;
            if (t > 0) {
                const u64* ph = hpOwn + (size_t)(t - 1) * HDIM + tid;
                u64 vb; bool ra = false, rb = false;
                for (;;) {
                    if (!ra) { va = cohLoad(px); ra = ((unsigned)(va >> 32) == t + 1u); }
                    if (!rb) { vb = cohLoad(ph); rb = ((unsigned)(vb >> 32) == t); }
                    if (ra & rb) break;
                }
                h_in[pb][HDIM + tid] = __uint_as_float((unsigned)vb);
            } else {
                do { va = cohLoad(px); } while ((unsigned)(va >> 32) != 1u);
                h_in[pb][HDIM + tid] = 0.f;
            }
            h_in[pb][tid] = __uint_as_float((unsigned)va);
        }
        __syncthreads();

        // ---- this lane's 64-k dot; w index loop-constant (no scratch) ----
        float p = 0.f;
        if (layer == 0) {
            const float4* base = (const float4*)(h_in[pb]) + j * 8;
            #pragma unroll
            for (int i = 0; i < 8; ++i) {
                float4 hv = base[(i + j) & 7];     // staggered, 2-way max
                p += w[4*i+0]*hv.x + w[4*i+1]*hv.y
                   + w[4*i+2]*hv.z + w[4*i+3]*hv.w;
            }
            float2 xv = ((const float2*)x_lds[pb])[j];
            p += w[32]*xv.x + w[33]*xv.y;
        } else {
            const float4* base = (const float4*)(h_in[pb]) + j * 16;
            #pragma unroll
            for (int i = 0; i < 16; ++i) {
                float4 hv = base[(i + j) & 15];    // staggered, 2-way max
                p += w[4*i+0]*hv.x + w[4*i+1]*hv.y
                   + w[4*i+2]*hv.z + w[4*i+3]*hv.w;
            }
        }
        // ---- 16-lane butterfly: row sum in every lane of the row group ----
        p += __shfl_xor(p, 1, 64);
        p += __shfl_xor(p, 2, 64);
        p += __shfl_xor(p, 4, 64);
        p += __shfl_xor(p, 8, 64);
        float tot = p + brow;

        // ---- lane 0 gathers f,g,o row sums; gates; publish ----
        float af = __shfl(tot, 16, 64);
        float ag = __shfl(tot, 32, 64);
        float ao = __shfl(tot, 48, 64);
        if (lane == 0) {
            float iv = fsigmoid(tot);
            float fv = fsigmoid(af);
            float gv = ftanh(ag);
            float ov = fsigmoid(ao);
            c = fv * c + iv * gv;
            float h = ov * ftanh(c);
            u64 pkt = (u64)__float_as_uint(h) | ((u64)(t + 1u) << 32);
            cohStore(hpOwn + (size_t)t * HDIM + col, pkt);
        }
        // single barrier per step: next stage writes the other buffer.
    }
}

// ---------------------------------------------------------------------------
extern "C" void kernel_launch(void* const* d_in, const int* in_sizes, int n_in,
                              void* d_out, int out_size, void* d_ws, size_t ws_size,
                              hipStream_t stream) {
    const float* seq   = (const float*)d_in[0];
    const float* W_ih1 = (const float*)d_in[1];
    const float* W_hh1 = (const float*)d_in[2];
    const float* b_ih1 = (const float*)d_in[3];
    const float* b_hh1 = (const float*)d_in[4];
    const float* W_ih2 = (const float*)d_in[5];
    const float* W_hh2 = (const float*)d_in[6];
    const float* b_ih2 = (const float*)d_in[7];
    const float* b_hh2 = (const float*)d_in[8];
    const float* W_ih3 = (const float*)d_in[9];
    const float* W_hh3 = (const float*)d_in[10];
    const float* b_ih3 = (const float*)d_in[11];
    const float* b_hh3 = (const float*)d_in[12];
    const float* W_out = (const float*)d_in[13];
    const float* b_out = (const float*)d_in[14];
    float* out = (float*)d_out;

    // Workspace: hp[3][T][512] packed u64 (50.3MB); hs2 floats reuse the
    // dead layer-0 packed region after the recurrence.
    u64*   hp   = (u64*)d_ws;
    float* hs2f = (float*)d_ws;
    const u64* hp2 = hp + (size_t)2 * T_SEQ * HDIM;

    hipMemsetAsync(hp, 0, (size_t)3 * T_SEQ * HDIM * sizeof(u64), stream);

    lstm_fused<<<3 * NWG_L, NTH, 0, stream>>>(
        seq, W_ih1, W_hh1, b_ih1, b_hh1, W_ih2, W_hh2, b_ih2, b_hh2,
        W_ih3, W_hh3, b_ih3, b_hh3, hp);

    const int n = T_SEQ * HDIM;
    unpack_h<<<(n + 255) / 256, 256, 0, stream>>>(hp2, hs2f, n);

    gemm_abt<64, 32, 32><<<dim3(1, T_SEQ / 64), 256, 0, stream>>>(
        hs2f, W_out, b_out, out, T_SEQ, 32, HDIM);
}

// Round 7
// 7618.253 us; speedup vs baseline: 1.5856x; 1.5856x over previous
//
#include <hip/hip_runtime.h>

// LSTM T=4096, IN=32, H=512, OUT=32, 3 layers + projection.
// R7 = every verified lesson combined:
//   - R2 lesson: no cache-wide fences; relaxed agent-scope atomics only.
//   - R4 lesson: never index private arrays with runtime values.
//   - R5/R6 lesson: <=64 weight floats/lane (128 always spills).
//   - R6 lesson: publish must be ONE wave storing a FULL 128B line
//     (scattered 8B stores from 16 waves caused 4x writeback ping-pong:
//     WRITE_SIZE 192MB vs 48MB data), and fewer WGs = less poll contention.
// Config: 32 WGs/layer x 1024 threads (16 waves). Wave wv owns k-chunk
//   [wv*64,(wv+1)*64) of the K=1024 concat [prev-h;own-h] (layers 1/2) or
//   [wv*32..] of own-h + 2 x-terms (layer 0). Lane = row (gate*16+cl).
//   w[] = 64 floats/lane, loop-constant indexing, broadcast LDS reads.
//   Wave 0 tail: cross-wave reduce from LDS, gates, ONE coalesced 128B
//   publish (lanes 0-15, consecutive u64).
// Handoff: packed u64 {seq-tag:32 | value:32}, one poll per thread.

#define T_SEQ 4096
#define HDIM  512
#define NWG_L 32
#define NTH   1024

typedef unsigned long long u64;

__device__ __forceinline__ u64 cohLoad(const u64* p) {
    return __hip_atomic_load(p, __ATOMIC_RELAXED, __HIP_MEMORY_SCOPE_AGENT);
}
__device__ __forceinline__ void cohStore(u64* p, u64 v) {
    __hip_atomic_store(p, v, __ATOMIC_RELAXED, __HIP_MEMORY_SCOPE_AGENT);
}
__device__ __forceinline__ float fsigmoid(float x) {
    return __builtin_amdgcn_rcpf(1.f + __expf(-x));
}
__device__ __forceinline__ float ftanh(float x) {
    float e = __expf(2.f * fabsf(x));           // +inf ok -> t = 1
    float t = 1.f - 2.f * __builtin_amdgcn_rcpf(e + 1.f);
    return copysignf(t, x);
}

// ---------------------------------------------------------------------------
// Tiled fp32 GEMM (final projection): C[M][N] = A[M][K] * B[N][K]^T + bias[n]
// ---------------------------------------------------------------------------
template <int BM, int BN, int BK>
__global__ __launch_bounds__(256)
void gemm_abt(const float* __restrict__ A, const float* __restrict__ B,
              const float* __restrict__ bias1,
              float* __restrict__ C, int M, int N, int K) {
    constexpr int NTX = BN / 4;
    constexpr int NTY = 256 / NTX;
    constexpr int TM  = BM / NTY;
    __shared__ float As[BM][BK + 1];
    __shared__ float Bs[BN][BK + 1];

    const int tid = threadIdx.x;
    const int tx = tid % NTX;
    const int ty = tid / NTX;
    const int m0 = blockIdx.y * BM;
    const int n0 = blockIdx.x * BN;

    float acc[TM][4];
    #pragma unroll
    for (int i = 0; i < TM; ++i)
        #pragma unroll
        for (int j = 0; j < 4; ++j) acc[i][j] = 0.f;

    for (int k0 = 0; k0 < K; k0 += BK) {
        constexpr int AV = BM * BK / 4;
        #pragma unroll
        for (int i = tid; i < AV; i += 256) {
            int r = i / (BK / 4), c4 = i % (BK / 4);
            float4 v = *(const float4*)(A + (size_t)(m0 + r) * K + k0 + c4 * 4);
            As[r][c4 * 4 + 0] = v.x; As[r][c4 * 4 + 1] = v.y;
            As[r][c4 * 4 + 2] = v.z; As[r][c4 * 4 + 3] = v.w;
        }
        constexpr int BV = BN * BK / 4;
        #pragma unroll
        for (int i = tid; i < BV; i += 256) {
            int r = i / (BK / 4), c4 = i % (BK / 4);
            float4 v = *(const float4*)(B + (size_t)(n0 + r) * K + k0 + c4 * 4);
            Bs[r][c4 * 4 + 0] = v.x; Bs[r][c4 * 4 + 1] = v.y;
            Bs[r][c4 * 4 + 2] = v.z; Bs[r][c4 * 4 + 3] = v.w;
        }
        __syncthreads();
        #pragma unroll
        for (int kk = 0; kk < BK; ++kk) {
            float a[TM], b[4];
            #pragma unroll
            for (int i = 0; i < TM; ++i) a[i] = As[ty * TM + i][kk];
            #pragma unroll
            for (int j = 0; j < 4; ++j) b[j] = Bs[tx * 4 + j][kk];
            #pragma unroll
            for (int i = 0; i < TM; ++i)
                #pragma unroll
                for (int j = 0; j < 4; ++j) acc[i][j] += a[i] * b[j];
        }
        __syncthreads();
    }

    #pragma unroll
    for (int j = 0; j < 4; ++j) {
        float bv = bias1 ? bias1[n0 + tx * 4 + j] : 0.f;
        #pragma unroll
        for (int i = 0; i < TM; ++i) acc[i][j] += bv;
    }
    #pragma unroll
    for (int i = 0; i < TM; ++i) {
        int m = m0 + ty * TM + i;
        float4 v = make_float4(acc[i][0], acc[i][1], acc[i][2], acc[i][3]);
        *(float4*)(C + (size_t)m * N + n0 + tx * 4) = v;
    }
}

// ---------------------------------------------------------------------------
__global__ void unpack_h(const u64* __restrict__ hp, float* __restrict__ out,
                         int n) {
    int i = blockIdx.x * blockDim.x + threadIdx.x;
    if (i < n) out[i] = __uint_as_float((unsigned)hp[i]);
}

// ---------------------------------------------------------------------------
__global__ __launch_bounds__(NTH, 4)
void lstm_fused(const float* __restrict__ seq,
                const float* __restrict__ Wih1, const float* __restrict__ Whh1,
                const float* __restrict__ bih1, const float* __restrict__ bhh1,
                const float* __restrict__ Wih2, const float* __restrict__ Whh2,
                const float* __restrict__ bih2, const float* __restrict__ bhh2,
                const float* __restrict__ Wih3, const float* __restrict__ Whh3,
                const float* __restrict__ bih3, const float* __restrict__ bhh3,
                u64* __restrict__ hp) {
    // layers 1/2: h_in = [prev-h(512) | own-h(512)]
    // layer 0:    h_in = [own-h(512) | x(32) | unused]
    __shared__ __align__(16) float h_in[2][1024 + 32];
    __shared__ float part[16 * 64];

    const int blk   = blockIdx.x;
    const int layer = blk >> 5;
    const int g     = blk & 31;
    const int tid   = threadIdx.x;
    const int wv    = tid >> 6;          // 0..15
    const int lane  = tid & 63;
    const int gate  = lane >> 4;         // 0..3 (i,f,g,o)
    const int cl    = lane & 15;         // column-local
    const int grow  = gate * HDIM + g * 16 + cl;   // global gate row

    const float* Wih = layer == 0 ? Wih1 : (layer == 1 ? Wih2 : Wih3);
    const float* Whh = layer == 0 ? Whh1 : (layer == 1 ? Whh2 : Whh3);
    const float* bih = layer == 0 ? bih1 : (layer == 1 ? bih2 : bih3);
    const float* bhh = layer == 0 ? bhh1 : (layer == 1 ? bhh2 : bhh3);

    // ---- 64 weight floats/lane into registers (loop-constant indexing) ----
    float w[64];
    #pragma unroll
    for (int m = 0; m < 64; ++m) w[m] = 0.f;
    if (layer == 0) {
        // own-h chunk [wv*32, +32) -> w[0..31]; x chunk [wv*2, +2) -> w[32..33]
        const float* wp = Whh + (size_t)grow * HDIM + wv * 32;
        #pragma unroll
        for (int i = 0; i < 8; ++i) {
            float4 v = ((const float4*)wp)[i];
            w[4*i+0]=v.x; w[4*i+1]=v.y; w[4*i+2]=v.z; w[4*i+3]=v.w;
        }
        float2 xw = *(const float2*)(Wih + (size_t)grow * 32 + 2 * wv);
        w[32] = xw.x; w[33] = xw.y;
    } else {
        const float* wp = (wv < 8)
            ? Wih + (size_t)grow * HDIM + wv * 64
            : Whh + (size_t)grow * HDIM + (wv - 8) * 64;
        #pragma unroll
        for (int i = 0; i < 16; ++i) {
            float4 v = ((const float4*)wp)[i];
            w[4*i+0]=v.x; w[4*i+1]=v.y; w[4*i+2]=v.z; w[4*i+3]=v.w;
        }
    }
    #pragma unroll
    for (int m = 0; m < 64; ++m) asm volatile("" : "+v"(w[m]));

    const float brow = bih[grow] + bhh[grow];   // bias of this lane's row

    u64*       hpOwn  = hp + (size_t)layer * T_SEQ * HDIM;
    const u64* hpPrev = hp + (size_t)(layer > 0 ? layer - 1 : 0) * T_SEQ * HDIM;

    float c = 0.f;   // cell state (wave 0, lanes 0..15)

    for (unsigned t = 0; t < T_SEQ; ++t) {
        const int pb = t & 1;
        // ---- stage: each thread polls exactly one element ----
        if (layer == 0) {
            if (tid < HDIM) {
                float hv = 0.f;
                if (t > 0) {
                    const u64* ph = hpOwn + (size_t)(t - 1) * HDIM + tid;
                    u64 v;
                    do { v = cohLoad(ph); } while ((unsigned)(v >> 32) != t);
                    hv = __uint_as_float((unsigned)v);
                }
                h_in[pb][tid] = hv;
            } else if (tid < HDIM + 32) {
                h_in[pb][tid] = seq[(size_t)t * 32 + (tid - HDIM)];
            }
        } else {
            if (tid < HDIM) {                    // prev-layer h[t], tag t+1
                const u64* px = hpPrev + (size_t)t * HDIM + tid;
                u64 v;
                do { v = cohLoad(px); } while ((unsigned)(v >> 32) != t + 1u);
                h_in[pb][tid] = __uint_as_float((unsigned)v);
            } else {                             // own h[t-1], tag t
                float hv = 0.f;
                if (t > 0) {
                    const u64* ph = hpOwn + (size_t)(t - 1) * HDIM + (tid - HDIM);
                    u64 v;
                    do { v = cohLoad(ph); } while ((unsigned)(v >> 32) != t);
                    hv = __uint_as_float((unsigned)v);
                }
                h_in[pb][tid] = hv;
            }
        }
        __syncthreads();

        // ---- this lane's 64-MAC dot; broadcast LDS reads, const w idx ----
        float p = 0.f;
        if (layer == 0) {
            const float4* base = (const float4*)(h_in[pb]) + wv * 8;
            #pragma unroll
            for (int i = 0; i < 8; ++i) {
                float4 hv = base[i];             // same addr across wave
                p += w[4*i+0]*hv.x + w[4*i+1]*hv.y
                   + w[4*i+2]*hv.z + w[4*i+3]*hv.w;
            }
            float2 xv = ((const float2*)(h_in[pb] + HDIM))[wv];
            p += w[32]*xv.x + w[33]*xv.y;
        } else {
            const float4* base = (const float4*)(h_in[pb]) + wv * 16;
            #pragma unroll
            for (int i = 0; i < 16; ++i) {
                float4 hv = base[i];
                p += w[4*i+0]*hv.x + w[4*i+1]*hv.y
                   + w[4*i+2]*hv.z + w[4*i+3]*hv.w;
            }
        }
        part[wv * 64 + lane] = p;
        __syncthreads();

        // ---- wave 0: cross-wave reduce, gates, ONE coalesced publish ----
        if (wv == 0) {
            float tot = brow;
            #pragma unroll
            for (int wvv = 0; wvv < 16; ++wvv) tot += part[wvv * 64 + lane];
            float ai = __shfl(tot, cl +  0, 64);
            float af = __shfl(tot, cl + 16, 64);
            float ag = __shfl(tot, cl + 32, 64);
            float ao = __shfl(tot, cl + 48, 64);
            if (lane < 16) {
                float iv = fsigmoid(ai);
                float fv = fsigmoid(af);
                float gv = ftanh(ag);
                float ov = fsigmoid(ao);
                c = fv * c + iv * gv;
                float h = ov * ftanh(c);
                u64 pkt = (u64)__float_as_uint(h) | ((u64)(t + 1u) << 32);
                // lanes 0-15: 16 consecutive u64 = one 128B line
                cohStore(hpOwn + (size_t)t * HDIM + g * 16 + lane, pkt);
            }
        }
        // other waves roll straight into polling step t+1 (other buffer).
    }
}

// ---------------------------------------------------------------------------
extern "C" void kernel_launch(void* const* d_in, const int* in_sizes, int n_in,
                              void* d_out, int out_size, void* d_ws, size_t ws_size,
                              hipStream_t stream) {
    const float* seq   = (const float*)d_in[0];
    const float* W_ih1 = (const float*)d_in[1];
    const float* W_hh1 = (const float*)d_in[2];
    const float* b_ih1 = (const float*)d_in[3];
    const float* b_hh1 = (const float*)d_in[4];
    const float* W_ih2 = (const float*)d_in[5];
    const float* W_hh2 = (const float*)d_in[6];
    const float* b_ih2 = (const float*)d_in[7];
    const float* b_hh2 = (const float*)d_in[8];
    const float* W_ih3 = (const float*)d_in[9];
    const float* W_hh3 = (const float*)d_in[10];
    const float* b_ih3 = (const float*)d_in[11];
    const float* b_hh3 = (const float*)d_in[12];
    const float* W_out = (const float*)d_in[13];
    const float* b_out = (const float*)d_in[14];
    float* out = (float*)d_out;

    // Workspace: hp[3][T][512] packed u64 (50.3MB); hs2 floats reuse the
    // dead layer-0 packed region after the recurrence.
    u64*   hp   = (u64*)d_ws;
    float* hs2f = (float*)d_ws;
    const u64* hp2 = hp + (size_t)2 * T_SEQ * HDIM;

    hipMemsetAsync(hp, 0, (size_t)3 * T_SEQ * HDIM * sizeof(u64), stream);

    lstm_fused<<<3 * NWG_L, NTH, 0, stream>>>(
        seq, W_ih1, W_hh1, b_ih1, b_hh1, W_ih2, W_hh2, b_ih2, b_hh2,
        W_ih3, W_hh3, b_ih3, b_hh3, hp);

    const int n = T_SEQ * HDIM;
    unpack_h<<<(n + 255) / 256, 256, 0, stream>>>(hp2, hs2f, n);

    gemm_abt<64, 32, 32><<<dim3(1, T_SEQ / 64), 256, 0, stream>>>(
        hs2f, W_out, b_out, out, T_SEQ, 32, HDIM);
}